// Round 4
// baseline (412.050 us; speedup 1.0000x reference)
//
#include <hip/hip_runtime.h>

// YOLO loss: S=7, B=2, C=80. preds cell = 90 f32, target cell = 85 f32.
// Output: 4 f32 scalars (coords, obj, noobj, classes) over 401408 cells.
//
// R4: flat coalesced scan + tiny LDS box buffer.
//   R1 thread-per-cell: scattered-address wall (~110 cyc/VMEM instr, 64 lines/instr).
//   R2 45KB LDS tiles:  occupancy (2 blocks/CU) + barrier latency.
//   R3 wave-per-cell:   VALU-bound, box math masked to 1/64 lanes.
// Here: per 64-cell tile, all 256 threads scan the 5760 pred floats by flat
// index (fully coalesced), co-loading the matching targ element; class loss
// is computed inline (obj pre-staged, 64 floats), box fields stashed to a
// 4.4 KB LDS buffer; then threads 0-63 do box math lane-parallel from LDS.

#define NPRED 90
#define NTGT  85
#define NCLS  80
#define TILE  64
#define BLOCK 256

__device__ __forceinline__ float sgnf(float x) {
    return (x > 0.0f) ? 1.0f : ((x < 0.0f) ? -1.0f : 0.0f);
}

__global__ __launch_bounds__(BLOCK) void yolo_loss_kernel(
    const float* __restrict__ preds, const float* __restrict__ targ,
    float* __restrict__ out, int n_cells, int n_tiles)
{
    __shared__ float s_obj[TILE];
    __shared__ float s_pbox[TILE * 11];  // p[80..89], stride 11 -> 2-way banks (free)
    __shared__ float s_tbox[TILE * 5];   // tcx,tcy,tw,th, stride 5 -> 2-way (free)
    __shared__ float red[4][4];

    const int tid = threadIdx.x;
    float coords = 0.0f, objl = 0.0f, noobjl = 0.0f, clsl = 0.0f;

    for (int tile = blockIdx.x; tile < n_tiles; tile += gridDim.x) {
        int cell0 = tile * TILE;
        int ncell = min(TILE, n_cells - cell0);
        const float* pb = preds + (size_t)cell0 * NPRED;
        const float* tb = targ  + (size_t)cell0 * NTGT;

        __syncthreads();  // prev tile's step-3 readers done before we rewrite LDS
        if (tid < ncell) s_obj[tid] = tb[tid * NTGT + NCLS];  // obj = t[80]
        __syncthreads();

        // ---- flat coalesced scan of this tile's pred block ----
        int nelem = ncell * NPRED;
        for (int j = tid; j < nelem; j += BLOCK) {
            unsigned cell = (unsigned)j / 90u;   // magic-mul
            int field = j - (int)cell * 90;
            float p = pb[j];
            if (field < 85) {
                float tv = tb[(int)cell * 85 + field];  // coalesced-ish co-load
                if (field < 80) {
                    float d = fmaf(p, s_obj[cell], -tv);
                    clsl = fmaf(d, d, clsl);
                } else {
                    if (field >= 81) s_tbox[cell * 5 + (field - 81)] = tv;
                    s_pbox[cell * 11 + (field - 80)] = p;
                }
            } else {
                s_pbox[cell * 11 + (field - 80)] = p;
            }
        }
        __syncthreads();

        // ---- box math: one thread per cell, lane-parallel ----
        if (tid < ncell) {
            const float* pc = s_pbox + tid * 11;
            float obj = s_obj[tid];
            float P80 = pc[0], P81 = pc[1], P82 = pc[2], P83 = pc[3], P84 = pc[4];
            float P85 = pc[5], P86 = pc[6], P87 = pc[7], P88 = pc[8], P89 = pc[9];
            float tcx = s_tbox[tid * 5 + 0], tcy = s_tbox[tid * 5 + 1];
            float tw  = s_tbox[tid * 5 + 2], th  = s_tbox[tid * 5 + 3];

            float bx1 = tcx - tw * 0.5f, by1 = tcy - th * 0.5f;
            float bx2 = tcx + tw * 0.5f, by2 = tcy + th * 0.5f;
            float area_b = (bx2 - bx1) * (by2 - by1);

            // box1 = p[86..89]
            float ax1 = P86 - P88 * 0.5f, ay1 = P87 - P89 * 0.5f;
            float ax2 = P86 + P88 * 0.5f, ay2 = P87 + P89 * 0.5f;
            float iw = fmaxf(fminf(ax2, bx2) - fmaxf(ax1, bx1), 0.0f);
            float ih = fmaxf(fminf(ay2, by2) - fmaxf(ay1, by1), 0.0f);
            float inter1 = iw * ih;
            float area1 = (ax2 - ax1) * (ay2 - ay1);
            float iou1 = inter1 / (area1 + area_b - inter1);

            // box2 = p[81..84]
            float cx1 = P81 - P83 * 0.5f, cy1 = P82 - P84 * 0.5f;
            float cx2 = P81 + P83 * 0.5f, cy2 = P82 + P84 * 0.5f;
            float jw = fmaxf(fminf(cx2, bx2) - fmaxf(cx1, bx1), 0.0f);
            float jh = fmaxf(fminf(cy2, by2) - fmaxf(cy1, by1), 0.0f);
            float inter2 = jw * jh;
            float area2 = (cx2 - cx1) * (cy2 - cy1);
            float iou2 = inter2 / (area2 + area_b - inter2);

            bool use2 = iou2 > iou1;  // argmax: tie -> box1

            float pcx = obj * (use2 ? P81 : P86);
            float pw  = obj * (use2 ? P83 : P88);
            float ph  = obj * (use2 ? P84 : P89);

            // center loss uses ONLY cx (ref's [..., :-3] on a 4-vector)
            float dc = pcx - tcx;
            float dw = sgnf(pw) * sqrtf(fabsf(pw) + 1e-6f) - sqrtf(tw);
            float dh = sgnf(ph) * sqrtf(fabsf(ph) + 1e-6f) - sqrtf(th);
            coords = fmaf(dc, dc, coords);
            coords = fmaf(dw, dw, coords);
            coords = fmaf(dh, dh, coords);

            float obj_pred = use2 ? P80 : P85;
            float e1 = fmaf(obj, obj_pred, -obj);
            objl = fmaf(e1, e1, objl);
            float e2 = fmaf(1.0f - obj, obj_pred, -obj);
            noobjl = fmaf(e2, e2, noobjl);
        }
    }

    // ---- wave reduce (64 lanes) ----
    #pragma unroll
    for (int off = 32; off > 0; off >>= 1) {
        coords += __shfl_down(coords, off);
        objl   += __shfl_down(objl, off);
        noobjl += __shfl_down(noobjl, off);
        clsl   += __shfl_down(clsl, off);
    }

    int wave = tid >> 6;
    int lane = tid & 63;
    __syncthreads();  // LDS reuse safety before writing red[][]
    if (lane == 0) {
        red[0][wave] = coords;
        red[1][wave] = objl;
        red[2][wave] = noobjl;
        red[3][wave] = clsl;
    }
    __syncthreads();
    if (tid == 0) {
        float cd = red[0][0] + red[0][1] + red[0][2] + red[0][3];
        float o  = red[1][0] + red[1][1] + red[1][2] + red[1][3];
        float n  = red[2][0] + red[2][1] + red[2][2] + red[2][3];
        float k  = red[3][0] + red[3][1] + red[3][2] + red[3][3];
        atomicAdd(&out[0], 5.0f * cd);  // LAMBDA_COORDS
        atomicAdd(&out[1], o);
        atomicAdd(&out[2], 0.5f * n);   // LAMBDA_NOOBJ
        atomicAdd(&out[3], k);
    }
}

extern "C" void kernel_launch(void* const* d_in, const int* in_sizes, int n_in,
                              void* d_out, int out_size, void* d_ws, size_t ws_size,
                              hipStream_t stream) {
    const float* preds = (const float*)d_in[0];
    const float* targ  = (const float*)d_in[1];
    float* out = (float*)d_out;

    int n_cells = in_sizes[0] / NPRED;              // 401408
    int n_tiles = (n_cells + TILE - 1) / TILE;      // 6272

    hipMemsetAsync(d_out, 0, (size_t)out_size * sizeof(float), stream);

    // 4.4 KB LDS -> occupancy capped by waves only: 8 blocks/CU resident
    int blocks = 2048;
    if (blocks > n_tiles) blocks = n_tiles;
    hipLaunchKernelGGL(yolo_loss_kernel, dim3(blocks), dim3(BLOCK), 0, stream,
                       preds, targ, out, n_cells, n_tiles);
}

// Round 5
// 336.563 us; speedup vs baseline: 1.2243x; 1.2243x over previous
//
#include <hip/hip_runtime.h>

// YOLO loss: S=7, B=2, C=80. preds cell = 90 f32, target cell = 85 f32.
// Output: 4 f32 scalars (coords, obj, noobj, classes) over 401408 cells.
//
// R5: async global_load_lds staged 32-cell tiles.
//   R1 thread-per-cell: scattered-address wall (64 lines/VMEM instr, ~110cyc).
//   R2 45KB LDS tiles:  2 blocks/CU -> barrier latency exposed.
//   R3 wave-per-cell:   VALU wasted on 1/64-lane box math.
//   R4 flat co-load:    per-element dependent chains, no MLP.
// Here: stage p-tile (2880 f32) + t-tile (2720 f32) contiguously into LDS via
// width-16 global_load_lds (coalesced, no VGPR round trip, ~22 wave-instrs),
// barrier, consume via conflict-free ds_read_b128 flat scan (class loss) +
// 32 lane-parallel threads for box math. 22.4KB LDS -> 7 blocks/CU so the
// stage->barrier->consume chain overlaps across blocks.

#define NPRED 90
#define NTGT  85
#define NCLS  80
#define TILE  32
#define BLOCK 256
#define NP_ELEM (TILE * NPRED)            // 2880 floats
#define NT_ELEM (TILE * NTGT)             // 2720 floats
#define NF4 ((NP_ELEM + NT_ELEM) / 4)     // 1400 float4 stage units

__device__ __forceinline__ float sgnf(float x) {
    return (x > 0.0f) ? 1.0f : ((x < 0.0f) ? -1.0f : 0.0f);
}

__global__ __launch_bounds__(BLOCK) void yolo_loss_kernel(
    const float* __restrict__ preds, const float* __restrict__ targ,
    float* __restrict__ out, int n_tiles)
{
    __shared__ __align__(16) float s_tile[NP_ELEM + NT_ELEM];  // 22400 B
    __shared__ float red[4][4];

    const int tid = threadIdx.x;
    float coords = 0.0f, objl = 0.0f, noobjl = 0.0f, clsl = 0.0f;

    const float* sp = s_tile;            // staged preds tile
    const float* st = s_tile + NP_ELEM;  // staged targ tile (16B-aligned: 11520B off)

    for (int tile = blockIdx.x; tile < n_tiles; tile += gridDim.x) {
        const float4* pb4 = (const float4*)(preds + (size_t)tile * NP_ELEM);
        const float4* tb4 = (const float4*)(targ  + (size_t)tile * NT_ELEM);

        // ---- async stage: p then t, contiguous in LDS (lane order == lds order) ----
        for (int f = tid; f < NF4; f += BLOCK) {
            const float4* g = (f < NP_ELEM / 4) ? (pb4 + f) : (tb4 + (f - NP_ELEM / 4));
            __builtin_amdgcn_global_load_lds(
                (const __attribute__((address_space(1))) void*)g,
                (__attribute__((address_space(3))) void*)(s_tile + f * 4),
                16, 0, 0);
        }
        __syncthreads();  // drains vmcnt (async loads) for all waves, then barrier

        // ---- class loss: flat float4 scan of p-tile from LDS ----
        for (int j4 = tid * 4; j4 < NP_ELEM; j4 += BLOCK * 4) {
            float4 pv = *(const float4*)(sp + j4);  // ds_read_b128, conflict-free
            int cell0 = (int)((unsigned)j4 / 90u);
            int r0 = j4 - cell0 * 90;
            int c1 = cell0 + 1; if (c1 >= TILE) c1 = TILE - 1;  // clamp (unused then)
            float obj0 = st[cell0 * NTGT + NCLS];
            float obj1 = st[c1 * NTGT + NCLS];
            float pe[4] = {pv.x, pv.y, pv.z, pv.w};
            #pragma unroll
            for (int e = 0; e < 4; ++e) {
                int f = r0 + e;
                int cell = cell0;
                float obj = obj0;
                if (f >= NPRED) { f -= NPRED; cell = c1; obj = obj1; }
                if (f < NCLS) {
                    float tv = st[cell * NTGT + f];
                    float d = fmaf(pe[e], obj, -tv);
                    clsl = fmaf(d, d, clsl);
                }
            }
        }

        // ---- box math: one thread per cell, lane-parallel, from staged LDS ----
        if (tid < TILE) {
            const float* pc = sp + tid * NPRED + 80;  // p[80..89]
            const float* tc = st + tid * NTGT + 80;   // t[80..84]
            float P80 = pc[0], P81 = pc[1], P82 = pc[2], P83 = pc[3], P84 = pc[4];
            float P85 = pc[5], P86 = pc[6], P87 = pc[7], P88 = pc[8], P89 = pc[9];
            float obj = tc[0];
            float tcx = tc[1], tcy = tc[2], tw = tc[3], th = tc[4];

            float bx1 = tcx - tw * 0.5f, by1 = tcy - th * 0.5f;
            float bx2 = tcx + tw * 0.5f, by2 = tcy + th * 0.5f;
            float area_b = (bx2 - bx1) * (by2 - by1);

            // box1 = p[86..89]
            float ax1 = P86 - P88 * 0.5f, ay1 = P87 - P89 * 0.5f;
            float ax2 = P86 + P88 * 0.5f, ay2 = P87 + P89 * 0.5f;
            float iw = fmaxf(fminf(ax2, bx2) - fmaxf(ax1, bx1), 0.0f);
            float ih = fmaxf(fminf(ay2, by2) - fmaxf(ay1, by1), 0.0f);
            float inter1 = iw * ih;
            float area1 = (ax2 - ax1) * (ay2 - ay1);
            float iou1 = inter1 / (area1 + area_b - inter1);

            // box2 = p[81..84]
            float cx1 = P81 - P83 * 0.5f, cy1 = P82 - P84 * 0.5f;
            float cx2 = P81 + P83 * 0.5f, cy2 = P82 + P84 * 0.5f;
            float jw = fmaxf(fminf(cx2, bx2) - fmaxf(cx1, bx1), 0.0f);
            float jh = fmaxf(fminf(cy2, by2) - fmaxf(cy1, by1), 0.0f);
            float inter2 = jw * jh;
            float area2 = (cx2 - cx1) * (cy2 - cy1);
            float iou2 = inter2 / (area2 + area_b - inter2);

            bool use2 = iou2 > iou1;  // argmax: tie -> box1

            float pcx = obj * (use2 ? P81 : P86);
            float pw  = obj * (use2 ? P83 : P88);
            float ph  = obj * (use2 ? P84 : P89);

            // center loss uses ONLY cx (ref's [..., :-3] on a 4-vector)
            float dc = pcx - tcx;
            float dw = sgnf(pw) * sqrtf(fabsf(pw) + 1e-6f) - sqrtf(tw);
            float dh = sgnf(ph) * sqrtf(fabsf(ph) + 1e-6f) - sqrtf(th);
            coords = fmaf(dc, dc, coords);
            coords = fmaf(dw, dw, coords);
            coords = fmaf(dh, dh, coords);

            float obj_pred = use2 ? P80 : P85;
            float e1 = fmaf(obj, obj_pred, -obj);
            objl = fmaf(e1, e1, objl);
            float e2 = fmaf(1.0f - obj, obj_pred, -obj);
            noobjl = fmaf(e2, e2, noobjl);
        }
        __syncthreads();  // all LDS reads done before next tile's stage overwrites
    }

    // ---- wave reduce (64 lanes) ----
    #pragma unroll
    for (int off = 32; off > 0; off >>= 1) {
        coords += __shfl_down(coords, off);
        objl   += __shfl_down(objl, off);
        noobjl += __shfl_down(noobjl, off);
        clsl   += __shfl_down(clsl, off);
    }

    int wave = tid >> 6;
    int lane = tid & 63;
    if (lane == 0) {
        red[0][wave] = coords;
        red[1][wave] = objl;
        red[2][wave] = noobjl;
        red[3][wave] = clsl;
    }
    __syncthreads();
    if (tid == 0) {
        float cd = red[0][0] + red[0][1] + red[0][2] + red[0][3];
        float o  = red[1][0] + red[1][1] + red[1][2] + red[1][3];
        float n  = red[2][0] + red[2][1] + red[2][2] + red[2][3];
        float k  = red[3][0] + red[3][1] + red[3][2] + red[3][3];
        atomicAdd(&out[0], 5.0f * cd);  // LAMBDA_COORDS
        atomicAdd(&out[1], o);
        atomicAdd(&out[2], 0.5f * n);   // LAMBDA_NOOBJ
        atomicAdd(&out[3], k);
    }
}

extern "C" void kernel_launch(void* const* d_in, const int* in_sizes, int n_in,
                              void* d_out, int out_size, void* d_ws, size_t ws_size,
                              hipStream_t stream) {
    const float* preds = (const float*)d_in[0];
    const float* targ  = (const float*)d_in[1];
    float* out = (float*)d_out;

    int n_cells = in_sizes[0] / NPRED;          // 401408
    int n_tiles = n_cells / TILE;               // 12544 (exact: 401408 = 32*12544)

    hipMemsetAsync(d_out, 0, (size_t)out_size * sizeof(float), stream);

    // 22.4 KB LDS -> 7 blocks/CU; 1792 blocks = 7/CU, exactly 7 tiles each
    int blocks = 1792;
    if (blocks > n_tiles) blocks = n_tiles;
    hipLaunchKernelGGL(yolo_loss_kernel, dim3(blocks), dim3(BLOCK), 0, stream,
                       preds, targ, out, n_tiles);
}